// Round 8
// baseline (714.648 us; speedup 1.0000x reference)
//
#include <hip/hip_runtime.h>
#include <math.h>

#define H  14
#define C  7
#define HC 98
#define FIN 256
#define NEG_SLOPE 0.2f

#define BSHIFT 7
#define BSIZE  128
#define NBUCK_MAX 1024

typedef __attribute__((ext_vector_type(8))) short short8;
typedef __attribute__((ext_vector_type(4))) float floatx4;

#define WT_ROWS   112            // 98 cols zero-padded to 7*16
#define WT_STRIDE 264            // 256 + 8 pad (bf16 units)
#define XA_STRIDE 40             // 32 + 8 pad (bf16 units)

// f32 -> bf16 bits, round-to-nearest-even
__device__ __forceinline__ unsigned bf16r(float f) {
    unsigned u = __float_as_uint(f);
    return (u + 0x7FFFu + ((u >> 16) & 1u)) >> 16;
}
__device__ __forceinline__ float bflo(unsigned w) { return __uint_as_float(w << 16); }
__device__ __forceinline__ float bfhi(unsigned w) { return __uint_as_float(w & 0xFFFF0000u); }

// ---------------- bucketed CSR construction (no self loops) ----------------

__global__ void k_zero(int* __restrict__ p, int n) {
    int i = blockIdx.x * blockDim.x + threadIdx.x;
    if (i < n) p[i] = 0;
}

__global__ __launch_bounds__(256) void k_hist(const int* __restrict__ ei, int E,
                                              int* __restrict__ gcnt, int nb) {
    __shared__ int hist[NBUCK_MAX];
    const int t = threadIdx.x;
    for (int i = t; i < nb; i += 256) hist[i] = 0;
    __syncthreads();
    const int stride = gridDim.x * 256;
    for (int e = blockIdx.x * 256 + t; e < E; e += stride)
        atomicAdd(&hist[ei[E + e] >> BSHIFT], 1);
    __syncthreads();
    for (int i = t; i < nb; i += 256)
        if (hist[i]) atomicAdd(gcnt + i, hist[i]);
}

__global__ __launch_bounds__(1024) void k_bscan(const int* __restrict__ gcnt,
                                                int* __restrict__ boff, int* __restrict__ bcur,
                                                int* __restrict__ row_ptr, int nb, int N) {
    __shared__ int sd[1024];
    int t = threadIdx.x;
    int own = (t < nb) ? gcnt[t] : 0;
    sd[t] = own;
    __syncthreads();
    #pragma unroll
    for (int off = 1; off < 1024; off <<= 1) {
        int v = (t >= off) ? sd[t - off] : 0;
        __syncthreads();
        sd[t] += v;
        __syncthreads();
    }
    if (t < nb) {
        boff[t + 1] = sd[t];
        bcur[t] = sd[t] - own;          // exclusive
        if (t == nb - 1) row_ptr[N] = sd[t];
    }
    if (t == 0) boff[0] = 0;
}

__global__ __launch_bounds__(256) void k_part(const int* __restrict__ ei, int E,
                                              int* __restrict__ bcur, int2* __restrict__ pedge,
                                              int nb) {
    __shared__ int hist[NBUCK_MAX];
    __shared__ int start[NBUCK_MAX];
    const int t = threadIdx.x;
    const int chunk = (E + gridDim.x - 1) / gridDim.x;
    const int c0 = blockIdx.x * chunk;
    const int c1 = min(c0 + chunk, E);
    for (int i = t; i < nb; i += 256) hist[i] = 0;
    __syncthreads();
    for (int e = c0 + t; e < c1; e += 256)
        atomicAdd(&hist[ei[E + e] >> BSHIFT], 1);
    __syncthreads();
    for (int i = t; i < nb; i += 256) {
        int h = hist[i];
        start[i] = h ? atomicAdd(bcur + i, h) : 0;
        hist[i] = 0;                     // reuse as local cursor
    }
    __syncthreads();
    for (int e = c0 + t; e < c1; e += 256) {
        int s = ei[e], d = ei[E + e];
        int b = d >> BSHIFT;
        int pos = start[b] + atomicAdd(&hist[b], 1);
        pedge[pos] = make_int2(s, d);
    }
}

__global__ __launch_bounds__(256) void k_bcsr(const int2* __restrict__ pedge,
                                              const int* __restrict__ boff,
                                              int* __restrict__ row_ptr, int* __restrict__ col,
                                              int N) {
    __shared__ int cnt[BSIZE];
    __shared__ int sc[BSIZE];
    __shared__ int cur[BSIZE];
    const int b  = blockIdx.x;
    const int t  = threadIdx.x;
    const int e0 = boff[b], e1 = boff[b + 1];
    const int base = b << BSHIFT;
    const int nv = min(BSIZE, N - base);
    if (t < BSIZE) cnt[t] = 0;
    __syncthreads();
    for (int e = e0 + t; e < e1; e += 256)
        atomicAdd(&cnt[pedge[e].y - base], 1);
    __syncthreads();
    if (t < BSIZE) sc[t] = cnt[t];
    __syncthreads();
    #pragma unroll
    for (int off = 1; off < BSIZE; off <<= 1) {
        int v = 0;
        if (t < BSIZE && t >= off) v = sc[t - off];
        __syncthreads();
        if (t < BSIZE) sc[t] += v;
        __syncthreads();
    }
    if (t < nv) {
        int excl = sc[t] - cnt[t];
        row_ptr[base + t] = e0 + excl;
        cur[t] = excl;
    }
    __syncthreads();
    for (int e = e0 + t; e < e1; e += 256) {
        int2 r = pedge[e];
        int d = r.y - base;
        int pos = e0 + atomicAdd(&cur[d], 1);
        col[pos] = r.x;
    }
}

// ---------------- layer-1 projection via MFMA ----------------

__global__ void k_convW(const float* __restrict__ W, unsigned short* __restrict__ WtG) {
    int id = blockIdx.x * blockDim.x + threadIdx.x;   // 112*256
    int n = id >> 8, k = id & 255;
    float v = (n < HC) ? W[k * HC + n] : 0.f;
    WtG[id] = (unsigned short)(__float_as_uint(v) >> 16);  // exact: inputs bf16-rounded
}

__global__ __launch_bounds__(256) void k_proj1_mfma(
    const float* __restrict__ x, const unsigned short* __restrict__ WtG,
    unsigned short* __restrict__ xhb, int N)
{
    __shared__ unsigned short wt_s[WT_ROWS * WT_STRIDE];  // 59136 B
    __shared__ unsigned short xa_s[64 * XA_STRIDE];       //  5120 B
    const int t  = threadIdx.x;
    const int wv = t >> 6;
    const int l  = t & 63;
    const int ln = l & 15;
    const int qd = l >> 4;
    const int rowBase = blockIdx.x * 64;

    #pragma unroll
    for (int i = 0; i < 14; ++i) {
        int f = i * 256 + t;            // uint4 index, 3584 total (32 per row)
        int r = f >> 5, pos = f & 31;
        *(uint4*)(wt_s + r * WT_STRIDE + pos * 8) = ((const uint4*)WtG)[f];
    }

    floatx4 acc[7] = {};

    for (int step = 0; step < 8; ++step) {
        const int k0 = step * 32;
        __syncthreads();
        #pragma unroll
        for (int i = 0; i < 2; ++i) {
            int idx = i * 256 + t;       // 512 float4 total
            int r = idx >> 3, c4 = idx & 7;
            int gr = rowBase + r; if (gr >= N) gr = N - 1;
            float4 v = *(const float4*)(x + (size_t)gr * FIN + k0 + c4 * 4);
            ushort4 u;
            u.x = (unsigned short)(__float_as_uint(v.x) >> 16);
            u.y = (unsigned short)(__float_as_uint(v.y) >> 16);
            u.z = (unsigned short)(__float_as_uint(v.z) >> 16);
            u.w = (unsigned short)(__float_as_uint(v.w) >> 16);
            *(ushort4*)(xa_s + r * XA_STRIDE + c4 * 4) = u;
        }
        __syncthreads();
        short8 a = *(const short8*)(xa_s + ((wv << 4) + ln) * XA_STRIDE + qd * 8);
        #pragma unroll
        for (int ct = 0; ct < 7; ++ct) {
            short8 b = *(const short8*)(wt_s + (ct * 16 + ln) * WT_STRIDE + k0 + qd * 8);
            acc[ct] = __builtin_amdgcn_mfma_f32_16x16x32_bf16(a, b, acc[ct], 0, 0, 0);
        }
    }

    // C/D: col = ln, row = qd*4 + r
    #pragma unroll
    for (int ct = 0; ct < 7; ++ct) {
        #pragma unroll
        for (int r = 0; r < 4; ++r) {
            int gr   = rowBase + (wv << 4) + (qd << 2) + r;
            int colg = ct * 16 + ln;
            if (gr < N && colg < HC)
                xhb[(size_t)gr * HC + colg] = (unsigned short)bf16r(acc[ct][r]);
        }
    }
}

// layer-1 pack, head-major: xpackH[h][n] = {7 msg bf16, src-logit bf16}, aldstH[h][n]
__global__ __launch_bounds__(256) void k_pack1_t(
    const unsigned short* __restrict__ xhb,
    const float* __restrict__ asrc, const float* __restrict__ adst,
    uint4* __restrict__ xpackH, float* __restrict__ aldstH, int N)
{
    __shared__ unsigned short xs[128 * HC];     // 25088 B
    __shared__ float as_s[HC], ad_s[HC];
    const int t = threadIdx.x;
    const int base = blockIdx.x * 128;
    const uint4* src = (const uint4*)(xhb + (size_t)base * HC);
    uint4* dst = (uint4*)xs;
    const int nvec = (128 * HC) / 8;            // 1568 (ws slab padded; safe over-read)
    for (int i = t; i < nvec; i += 256) dst[i] = src[i];
    if (t < HC) { as_s[t] = asrc[t]; ad_s[t] = adst[t]; }
    __syncthreads();
    for (int p = t; p < 128 * H; p += 256) {
        int h = p >> 7, nl = p & 127;
        int n = base + nl;
        if (n >= N) continue;
        const unsigned short* xp = xs + nl * HC + h * C;
        unsigned v[C];
        float s1 = 0.f, s2 = 0.f;
        #pragma unroll
        for (int c2 = 0; c2 < C; ++c2) {
            v[c2] = xp[c2];
            float f = bflo(v[c2]);
            s1 = fmaf(f, as_s[h * C + c2], s1);
            s2 = fmaf(f, ad_s[h * C + c2], s2);
        }
        uint4 pk;
        pk.x = v[0] | (v[1] << 16);
        pk.y = v[2] | (v[3] << 16);
        pk.z = v[4] | (v[5] << 16);
        pk.w = v[6] | (bf16r(s1) << 16);
        xpackH[(size_t)h * N + n] = pk;
        aldstH[(size_t)h * N + n] = s2;
    }
}

// ---------------- layer-2 projection + pack (head-major outputs) ----------------

__global__ __launch_bounds__(256) void k_proj2_pack(
    const float* __restrict__ h1, const float* __restrict__ W,
    const float* __restrict__ asrc, const float* __restrict__ adst,
    uint4* __restrict__ xpackH, float* __restrict__ aldstH, int N)
{
    __shared__ float Ws[C * HC];
    __shared__ float as_s[HC], ad_s[HC];
    const int t = threadIdx.x;
    for (int i = t; i < C * HC; i += 256) Ws[i] = W[i];
    if (t < HC) { as_s[t] = asrc[t]; ad_s[t] = adst[t]; }
    __syncthreads();
    int n = blockIdx.x * 256 + t;
    if (n >= N) return;
    float xr[C];
    #pragma unroll
    for (int c2 = 0; c2 < C; ++c2) xr[c2] = h1[(size_t)n * C + c2];
    #pragma unroll
    for (int h = 0; h < H; ++h) {
        float v[C], s1 = 0.f, s2 = 0.f;
        #pragma unroll
        for (int c2 = 0; c2 < C; ++c2) {
            float acc = 0.f;
            #pragma unroll
            for (int k = 0; k < C; ++k)
                acc = fmaf(xr[k], Ws[k * HC + h * C + c2], acc);
            v[c2] = acc;
            s1 = fmaf(acc, as_s[h * C + c2], s1);
            s2 = fmaf(acc, ad_s[h * C + c2], s2);
        }
        uint4 pk;
        pk.x = bf16r(v[0]) | (bf16r(v[1]) << 16);
        pk.y = bf16r(v[2]) | (bf16r(v[3]) << 16);
        pk.z = bf16r(v[4]) | (bf16r(v[5]) << 16);
        pk.w = bf16r(v[6]) | (bf16r(s1) << 16);
        xpackH[(size_t)h * N + n] = pk;    // coalesced across lanes per h
        aldstH[(size_t)h * N + n] = s2;
    }
}

// ---------------- aggregation phase A: per (node) at fixed head per block ----------------
// class = blockIdx%8 serves heads {class, class+8} (slot alternates) so, assuming the
// standard blockIdx%8 -> XCD round-robin, each XCD keeps <=2 head slices (3.2 MB) hot in L2.

__global__ __launch_bounds__(256) void k_aggA(
    const int* __restrict__ row_ptr, const int* __restrict__ col,
    const uint4* __restrict__ xpackH, const float* __restrict__ aldstH,
    uint4* __restrict__ valsH, int N)
{
    const int b    = blockIdx.x;
    const int cls  = b & 7;
    const int j    = b >> 3;
    const int head = cls + ((j & 1) << 3);
    if (head >= H) return;                 // classes 6,7 slot1: idle
    const int n = (j >> 1) * 256 + threadIdx.x;
    if (n >= N) return;

    const uint4* __restrict__ xp = xpackH + (size_t)head * N;
    const int e0  = row_ptr[n];
    const int deg = row_ptr[n + 1] - e0;
    const float ld = aldstH[(size_t)head * N + n];

    float m, den, mx[C];
    {   // implicit self loop
        uint4 pk = xp[n];
        float l = bfhi(pk.w) + ld;
        l = (l > 0.f) ? l : NEG_SLOPE * l;
        m = l; den = 1.f;
        mx[0] = bflo(pk.x); mx[1] = bfhi(pk.x);
        mx[2] = bflo(pk.y); mx[3] = bfhi(pk.y);
        mx[4] = bflo(pk.z); mx[5] = bfhi(pk.z);
        mx[6] = bflo(pk.w);
    }

    if (deg > 0) {
        const int last = deg - 1;
        // depth-4 record pipeline + 4-deep col queue (clamped indices: always valid)
        int c0 = col[e0];
        int c1 = col[e0 + min(1, last)];
        int c2 = col[e0 + min(2, last)];
        int c3 = col[e0 + min(3, last)];
        uint4 b0 = xp[c0], b1 = xp[c1], b2 = xp[c2], b3 = xp[c3];
        c0 = col[e0 + min(4, last)];
        c1 = col[e0 + min(5, last)];
        c2 = col[e0 + min(6, last)];
        c3 = col[e0 + min(7, last)];
        for (int i = 0; i < deg; ++i) {
            uint4 cur = b0;
            b0 = b1; b1 = b2; b2 = b3;
            b3 = xp[c0];
            c0 = c1; c1 = c2; c2 = c3;
            c3 = col[e0 + min(i + 8, last)];
            float l = bfhi(cur.w) + ld;
            l = (l > 0.f) ? l : NEG_SLOPE * l;
            float mn = fmaxf(m, l);
            float r  = __expf(m - mn);
            float p  = __expf(l - mn);
            den = den * r + p;
            mx[0] = fmaxf(mx[0] * r, p * bflo(cur.x));
            mx[1] = fmaxf(mx[1] * r, p * bfhi(cur.x));
            mx[2] = fmaxf(mx[2] * r, p * bflo(cur.y));
            mx[3] = fmaxf(mx[3] * r, p * bfhi(cur.y));
            mx[4] = fmaxf(mx[4] * r, p * bflo(cur.z));
            mx[5] = fmaxf(mx[5] * r, p * bfhi(cur.z));
            mx[6] = fmaxf(mx[6] * r, p * bflo(cur.w));
            m = mn;
        }
    }

    const float rd = 1.f / den;
    uint4 o;
    o.x = bf16r(mx[0] * rd) | (bf16r(mx[1] * rd) << 16);
    o.y = bf16r(mx[2] * rd) | (bf16r(mx[3] * rd) << 16);
    o.z = bf16r(mx[4] * rd) | (bf16r(mx[5] * rd) << 16);
    o.w = bf16r(mx[6] * rd);
    valsH[(size_t)head * N + n] = o;
}

// ---------------- aggregation phase B: head-mean + epilogue ----------------

template<int LAYER>
__global__ __launch_bounds__(256) void k_fin(
    const uint4* __restrict__ valsH, const float* __restrict__ bias,
    float* __restrict__ h1, float* __restrict__ out, int N)
{
    int n = blockIdx.x * 256 + threadIdx.x;
    if (n >= N) return;
    float s[C] = {0.f, 0.f, 0.f, 0.f, 0.f, 0.f, 0.f};
    #pragma unroll
    for (int h = 0; h < H; ++h) {
        uint4 v = valsH[(size_t)h * N + n];
        s[0] += bflo(v.x); s[1] += bfhi(v.x);
        s[2] += bflo(v.y); s[3] += bfhi(v.y);
        s[4] += bflo(v.z); s[5] += bfhi(v.z);
        s[6] += bflo(v.w);
    }
    if (LAYER == 1) {
        #pragma unroll
        for (int c2 = 0; c2 < C; ++c2)
            h1[(size_t)n * C + c2] = fmaxf(s[c2] * (1.f / H) + bias[c2], 0.f);
    } else {
        float fv[C], mv = -1e30f;
        #pragma unroll
        for (int c2 = 0; c2 < C; ++c2) {
            fv[c2] = s[c2] * (1.f / H) + bias[c2];
            mv = fmaxf(mv, fv[c2]);
        }
        float lse = 0.f;
        #pragma unroll
        for (int c2 = 0; c2 < C; ++c2) lse += __expf(fv[c2] - mv);
        lse = logf(lse);
        #pragma unroll
        for (int c2 = 0; c2 < C; ++c2)
            out[(size_t)n * C + c2] = fv[c2] - mv - lse;
    }
}

// ---------------- launch ----------------

static inline size_t align16(size_t v) { return (v + 15) & ~(size_t)15; }
static inline size_t max3(size_t a, size_t b, size_t c) {
    size_t m = a > b ? a : b; return m > c ? m : c;
}

extern "C" void kernel_launch(void* const* d_in, const int* in_sizes, int n_in,
                              void* d_out, int out_size, void* d_ws, size_t ws_size,
                              hipStream_t stream)
{
    const float* x     = (const float*)d_in[0];
    const int*   ei    = (const int*)d_in[1];
    const float* W1    = (const float*)d_in[2];
    const float* asrc1 = (const float*)d_in[3];
    const float* adst1 = (const float*)d_in[4];
    const float* b1    = (const float*)d_in[5];
    const float* W2    = (const float*)d_in[6];
    const float* asrc2 = (const float*)d_in[7];
    const float* adst2 = (const float*)d_in[8];
    const float* b2    = (const float*)d_in[9];

    const int N  = in_sizes[0] / FIN;   // 100000
    const int E  = in_sizes[1] / 2;     // 1600000
    const int nb = (N + BSIZE - 1) >> BSHIFT;   // 782

    char* w = (char*)d_ws;
    uint4* xpackH  = (uint4*)w; w += align16((size_t)N * H * 16);   // 22.4 MB
    // shared region: pedge (CSR build) -> xhb (proj1->pack1) -> valsH (aggA->fin)
    char*  shared  = w;
    size_t shsz    = max3((size_t)E * 8, ((size_t)N + 128) * HC * 2, (size_t)N * H * 16);
    w += align16(shsz);                                             // 22.4 MB
    int2*  pedge   = (int2*)shared;
    unsigned short* xhb = (unsigned short*)shared;
    uint4* valsH   = (uint4*)shared;
    float* aldstH  = (float*)w; w += align16((size_t)N * H * 4);    //  5.6 MB
    float* h1      = (float*)w; w += align16((size_t)N * C * 4);    //  2.8 MB
    int*   row_ptr = (int*)w;   w += align16((size_t)(N + 1) * 4);
    int*   col     = (int*)w;   w += align16((size_t)E * 4);        //  6.4 MB
    int*   gcnt    = (int*)w;   w += align16((size_t)nb * 4);
    int*   boff    = (int*)w;   w += align16((size_t)(nb + 1) * 4);
    int*   bcur    = (int*)w;   w += align16((size_t)nb * 4);
    unsigned short* WtG = (unsigned short*)w; w += align16((size_t)WT_ROWS * FIN * 2);

    const int nbN   = (N + 255) / 256;          // 391
    const int gAggA = 8 * 2 * nbN;              // 6256 (classes x slots x node-blocks)
    const int gMfma = (N + 63) / 64;
    const int g256N = (N + 255) / 256;
    const int gPack = (N + 127) / 128;

    // ---- bucketed CSR build (no self loops; rebuilt every call) ----
    k_zero<<<(nb + 255) / 256, 256, 0, stream>>>(gcnt, nb);
    k_hist<<<256, 256, 0, stream>>>(ei, E, gcnt, nb);
    k_bscan<<<1, 1024, 0, stream>>>(gcnt, boff, bcur, row_ptr, nb, N);
    k_part<<<256, 256, 0, stream>>>(ei, E, bcur, pedge, nb);
    k_bcsr<<<nb, 256, 0, stream>>>(pedge, boff, row_ptr, col, N);

    // ---- layer 1 ----
    k_convW<<<(WT_ROWS * FIN + 255) / 256, 256, 0, stream>>>(W1, WtG);
    k_proj1_mfma<<<gMfma, 256, 0, stream>>>(x, WtG, xhb, N);
    k_pack1_t<<<gPack, 256, 0, stream>>>(xhb, asrc1, adst1, xpackH, aldstH, N);
    k_aggA<<<gAggA, 256, 0, stream>>>(row_ptr, col, xpackH, aldstH, valsH, N);
    k_fin<1><<<g256N, 256, 0, stream>>>(valsH, b1, h1, (float*)d_out, N);

    // ---- layer 2 ----
    k_proj2_pack<<<g256N, 256, 0, stream>>>(h1, W2, asrc2, adst2, xpackH, aldstH, N);
    k_aggA<<<gAggA, 256, 0, stream>>>(row_ptr, col, xpackH, aldstH, valsH, N);
    k_fin<2><<<g256N, 256, 0, stream>>>(valsH, b2, h1, (float*)d_out, N);
}

// Round 9
// 479.262 us; speedup vs baseline: 1.4911x; 1.4911x over previous
//
#include <hip/hip_runtime.h>
#include <math.h>

#define H  14
#define C  7
#define HC 98
#define FIN 256
#define NEG_SLOPE 0.2f
#define NPB 32
#define AGG_BLOCK (NPB * H)   // 448 = 7 full waves

#define BSHIFT 9
#define BSIZE  512
#define NBUCK_MAX 256

typedef __attribute__((ext_vector_type(8))) short short8;
typedef __attribute__((ext_vector_type(4))) float floatx4;

#define WT_ROWS   112            // 98 cols zero-padded to 7*16
#define WT_STRIDE 264            // 256 + 8 pad (bf16 units)
#define XA_STRIDE 40             // 32 + 8 pad (bf16 units)
#define VS_STRIDE 99             // 98 + 1 pad (f32 units)

// f32 -> bf16 bits, round-to-nearest-even
__device__ __forceinline__ unsigned bf16r(float f) {
    unsigned u = __float_as_uint(f);
    return (u + 0x7FFFu + ((u >> 16) & 1u)) >> 16;
}
__device__ __forceinline__ float bflo(unsigned w) { return __uint_as_float(w << 16); }
__device__ __forceinline__ float bfhi(unsigned w) { return __uint_as_float(w & 0xFFFF0000u); }

// ---------------- bucketed CSR construction (no self loops) ----------------

__global__ void k_zero(int* __restrict__ p, int n) {
    int i = blockIdx.x * blockDim.x + threadIdx.x;
    if (i < n) p[i] = 0;
}

__global__ __launch_bounds__(256) void k_hist(const int* __restrict__ ei, int E,
                                              int* __restrict__ gcnt, int nb) {
    __shared__ int hist[NBUCK_MAX];
    const int t = threadIdx.x;
    for (int i = t; i < nb; i += 256) hist[i] = 0;
    __syncthreads();
    const int stride = gridDim.x * 256;
    for (int e = blockIdx.x * 256 + t; e < E; e += stride)
        atomicAdd(&hist[ei[E + e] >> BSHIFT], 1);
    __syncthreads();
    for (int i = t; i < nb; i += 256)
        if (hist[i]) atomicAdd(gcnt + i, hist[i]);
}

__global__ __launch_bounds__(1024) void k_bscan(const int* __restrict__ gcnt,
                                                int* __restrict__ boff, int* __restrict__ bcur,
                                                int* __restrict__ row_ptr, int nb, int N) {
    __shared__ int sd[1024];
    int t = threadIdx.x;
    int own = (t < nb) ? gcnt[t] : 0;
    sd[t] = own;
    __syncthreads();
    #pragma unroll
    for (int off = 1; off < 1024; off <<= 1) {
        int v = (t >= off) ? sd[t - off] : 0;
        __syncthreads();
        sd[t] += v;
        __syncthreads();
    }
    if (t < nb) {
        boff[t + 1] = sd[t];
        bcur[t] = sd[t] - own;          // exclusive
        if (t == nb - 1) row_ptr[N] = sd[t];
    }
    if (t == 0) boff[0] = 0;
}

__global__ __launch_bounds__(256) void k_part(const int* __restrict__ ei, int E,
                                              int* __restrict__ bcur, int2* __restrict__ pedge,
                                              int nb) {
    __shared__ int hist[NBUCK_MAX];
    __shared__ int start[NBUCK_MAX];
    const int t = threadIdx.x;
    const int chunk = (E + gridDim.x - 1) / gridDim.x;
    const int c0 = blockIdx.x * chunk;
    const int c1 = min(c0 + chunk, E);
    for (int i = t; i < nb; i += 256) hist[i] = 0;
    __syncthreads();
    for (int e = c0 + t; e < c1; e += 256)
        atomicAdd(&hist[ei[E + e] >> BSHIFT], 1);
    __syncthreads();
    for (int i = t; i < nb; i += 256) {
        int h = hist[i];
        start[i] = h ? atomicAdd(bcur + i, h) : 0;
        hist[i] = 0;                     // reuse as local cursor
    }
    __syncthreads();
    for (int e = c0 + t; e < c1; e += 256) {
        int s = ei[e], d = ei[E + e];
        int b = d >> BSHIFT;
        int pos = start[b] + atomicAdd(&hist[b], 1);
        pedge[pos] = make_int2(s, d);
    }
}

__global__ __launch_bounds__(512) void k_bcsr(const int2* __restrict__ pedge,
                                              const int* __restrict__ boff,
                                              int* __restrict__ row_ptr, int* __restrict__ col,
                                              int N) {
    __shared__ int cnt[BSIZE];
    __shared__ int sc[BSIZE];
    __shared__ int cur[BSIZE];
    const int b  = blockIdx.x;
    const int t  = threadIdx.x;
    const int e0 = boff[b], e1 = boff[b + 1];
    const int base = b << BSHIFT;
    const int nv = min(BSIZE, N - base);
    cnt[t] = 0;
    __syncthreads();
    for (int e = e0 + t; e < e1; e += 512)
        atomicAdd(&cnt[pedge[e].y - base], 1);
    __syncthreads();
    sc[t] = cnt[t];
    __syncthreads();
    #pragma unroll
    for (int off = 1; off < BSIZE; off <<= 1) {
        int v = (t >= off) ? sc[t - off] : 0;
        __syncthreads();
        sc[t] += v;
        __syncthreads();
    }
    if (t < nv) {
        int excl = sc[t] - cnt[t];
        row_ptr[base + t] = e0 + excl;
        cur[t] = excl;
    }
    __syncthreads();
    for (int e = e0 + t; e < e1; e += 512) {
        int2 r = pedge[e];
        int d = r.y - base;
        int pos = e0 + atomicAdd(&cur[d], 1);
        col[pos] = r.x;
    }
}

// ---------------- layer-1: MFMA projection fused with pack ----------------

// W1 [256][98] f32  ->  Wt bf16 [112][256] (transposed, zero-padded cols)
__global__ void k_convW(const float* __restrict__ W, unsigned short* __restrict__ WtG) {
    int id = blockIdx.x * blockDim.x + threadIdx.x;   // 112*256
    int n = id >> 8, k = id & 255;
    float v = (n < HC) ? W[k * HC + n] : 0.f;
    WtG[id] = (unsigned short)(__float_as_uint(v) >> 16);  // exact: inputs bf16-rounded
}

// xpack[n*H+h] = {7 msg bf16, src-logit bf16}; aldst[n*H+h] = dst logit f32
__global__ __launch_bounds__(256) void k_proj1_mfma(
    const float* __restrict__ x, const unsigned short* __restrict__ WtG,
    const float* __restrict__ asrc, const float* __restrict__ adst,
    uint4* __restrict__ xpack, float* __restrict__ aldst, int N)
{
    __shared__ unsigned short wt_s[WT_ROWS * WT_STRIDE];  // 59136 B (reused as f32 vals)
    __shared__ unsigned short xa_s[64 * XA_STRIDE];       //  5120 B
    __shared__ float as_s[HC], ad_s[HC];
    float* vals_s = (float*)wt_s;                          // 64*99*4 = 25344 B < 59136
    const int t  = threadIdx.x;
    const int wv = t >> 6;
    const int l  = t & 63;
    const int ln = l & 15;
    const int qd = l >> 4;
    const int rowBase = blockIdx.x * 64;

    #pragma unroll
    for (int i = 0; i < 14; ++i) {
        int f = i * 256 + t;            // uint4 index, 3584 total (32 per row)
        int r = f >> 5, pos = f & 31;
        *(uint4*)(wt_s + r * WT_STRIDE + pos * 8) = ((const uint4*)WtG)[f];
    }
    if (t < HC) { as_s[t] = asrc[t]; ad_s[t] = adst[t]; }

    floatx4 acc[7] = {};

    for (int step = 0; step < 8; ++step) {
        const int k0 = step * 32;
        __syncthreads();
        #pragma unroll
        for (int i = 0; i < 2; ++i) {
            int idx = i * 256 + t;       // 512 float4 total
            int r = idx >> 3, c4 = idx & 7;
            int gr = rowBase + r; if (gr >= N) gr = N - 1;
            float4 v = *(const float4*)(x + (size_t)gr * FIN + k0 + c4 * 4);
            ushort4 u;
            u.x = (unsigned short)(__float_as_uint(v.x) >> 16);
            u.y = (unsigned short)(__float_as_uint(v.y) >> 16);
            u.z = (unsigned short)(__float_as_uint(v.z) >> 16);
            u.w = (unsigned short)(__float_as_uint(v.w) >> 16);
            *(ushort4*)(xa_s + r * XA_STRIDE + c4 * 4) = u;
        }
        __syncthreads();
        short8 a = *(const short8*)(xa_s + ((wv << 4) + ln) * XA_STRIDE + qd * 8);
        #pragma unroll
        for (int ct = 0; ct < 7; ++ct) {
            short8 b = *(const short8*)(wt_s + (ct * 16 + ln) * WT_STRIDE + k0 + qd * 8);
            acc[ct] = __builtin_amdgcn_mfma_f32_16x16x32_bf16(a, b, acc[ct], 0, 0, 0);
        }
    }

    __syncthreads();                    // wt_s dead; reuse as vals_s
    // C/D: col = ln, row = qd*4 + r (local row = wv*16 + qd*4 + r)
    #pragma unroll
    for (int ct = 0; ct < 7; ++ct) {
        int colg = ct * 16 + ln;
        if (colg < HC) {
            #pragma unroll
            for (int r = 0; r < 4; ++r)
                vals_s[((wv << 4) + (qd << 2) + r) * VS_STRIDE + colg] = acc[ct][r];
        }
    }
    __syncthreads();

    // pack: 64 nodes x 14 heads = 896 records
    for (int p = t; p < 64 * H; p += 256) {
        int nl = p / H, h = p - nl * H;
        int gn = rowBase + nl;
        if (gn >= N) break;
        const float* vp = vals_s + nl * VS_STRIDE + h * C;
        unsigned v[C];
        float s1 = 0.f, s2 = 0.f;
        #pragma unroll
        for (int c2 = 0; c2 < C; ++c2) {
            float f = vp[c2];
            v[c2] = bf16r(f);
            s1 = fmaf(f, as_s[h * C + c2], s1);
            s2 = fmaf(f, ad_s[h * C + c2], s2);
        }
        uint4 pk;
        pk.x = v[0] | (v[1] << 16);
        pk.y = v[2] | (v[3] << 16);
        pk.z = v[4] | (v[5] << 16);
        pk.w = v[6] | (bf16r(s1) << 16);
        xpack[(size_t)gn * H + h] = pk;
        aldst[(size_t)gn * H + h] = s2;
    }
}

// ---------------- layer-2 projection + pack (thread per node) ----------------

__global__ __launch_bounds__(256) void k_proj2_pack(
    const float* __restrict__ h1, const float* __restrict__ W,
    const float* __restrict__ asrc, const float* __restrict__ adst,
    uint4* __restrict__ xpack, float* __restrict__ aldst, int N)
{
    __shared__ float Ws[C * HC];
    __shared__ float as_s[HC], ad_s[HC];
    const int t = threadIdx.x;
    for (int i = t; i < C * HC; i += 256) Ws[i] = W[i];
    if (t < HC) { as_s[t] = asrc[t]; ad_s[t] = adst[t]; }
    __syncthreads();
    int n = blockIdx.x * 256 + t;
    if (n >= N) return;
    float xr[C];
    #pragma unroll
    for (int c2 = 0; c2 < C; ++c2) xr[c2] = h1[(size_t)n * C + c2];
    #pragma unroll
    for (int h = 0; h < H; ++h) {
        float v[C], s1 = 0.f, s2 = 0.f;
        #pragma unroll
        for (int c2 = 0; c2 < C; ++c2) {
            float acc = 0.f;
            #pragma unroll
            for (int k = 0; k < C; ++k)
                acc = fmaf(xr[k], Ws[k * HC + h * C + c2], acc);
            v[c2] = acc;
            s1 = fmaf(acc, as_s[h * C + c2], s1);
            s2 = fmaf(acc, ad_s[h * C + c2], s2);
        }
        uint4 pk;
        pk.x = bf16r(v[0]) | (bf16r(v[1]) << 16);
        pk.y = bf16r(v[2]) | (bf16r(v[3]) << 16);
        pk.z = bf16r(v[4]) | (bf16r(v[5]) << 16);
        pk.w = bf16r(v[6]) | (bf16r(s1) << 16);
        xpack[(size_t)n * H + h] = pk;     // 224 B contiguous per thread
        aldst[(size_t)n * H + h] = s2;
    }
}

// ---------------- fused aggregation ----------------
// thread = (node, head); implicit self loop; depth-4 clamped prefetch pipeline

template<int LAYER>
__global__ __launch_bounds__(AGG_BLOCK) void k_agg(
    const int* __restrict__ row_ptr, const int* __restrict__ col,
    const uint4* __restrict__ xpack, const float* __restrict__ aldst,
    const float* __restrict__ bias,
    float* __restrict__ h1, float* __restrict__ out, int N)
{
    __shared__ float vals[NPB][HC];
    __shared__ float fv[NPB][C];
    const int t  = threadIdx.x;
    const int nl = t / H;
    const int h  = t - nl * H;
    const int n  = blockIdx.x * NPB + nl;

    if (n < N) {
        const int e0  = row_ptr[n];
        const int deg = row_ptr[n + 1] - e0;
        const float ld = aldst[(size_t)n * H + h];
        float m, den, mx[C];
        {   // implicit self loop
            uint4 pk = xpack[(size_t)n * H + h];
            float l = bfhi(pk.w) + ld;
            l = (l > 0.f) ? l : NEG_SLOPE * l;
            m = l; den = 1.f;
            mx[0] = bflo(pk.x); mx[1] = bfhi(pk.x);
            mx[2] = bflo(pk.y); mx[3] = bfhi(pk.y);
            mx[4] = bflo(pk.z); mx[5] = bfhi(pk.z);
            mx[6] = bflo(pk.w);
        }
        if (deg > 0) {
            const int last = deg - 1;
            uint4 b0 = xpack[(size_t)col[e0] * H + h];
            uint4 b1 = xpack[(size_t)col[e0 + min(1, last)] * H + h];
            uint4 b2 = xpack[(size_t)col[e0 + min(2, last)] * H + h];
            uint4 b3 = xpack[(size_t)col[e0 + min(3, last)] * H + h];
            for (int i = 0; i < deg; ++i) {
                uint4 cur = b0;
                b0 = b1; b1 = b2; b2 = b3;
                b3 = xpack[(size_t)col[e0 + min(i + 4, last)] * H + h];
                float l = bfhi(cur.w) + ld;
                l = (l > 0.f) ? l : NEG_SLOPE * l;
                float mn = fmaxf(m, l);
                float r  = __expf(m - mn);
                float p  = __expf(l - mn);
                den = den * r + p;
                mx[0] = fmaxf(mx[0] * r, p * bflo(cur.x));
                mx[1] = fmaxf(mx[1] * r, p * bfhi(cur.x));
                mx[2] = fmaxf(mx[2] * r, p * bflo(cur.y));
                mx[3] = fmaxf(mx[3] * r, p * bfhi(cur.y));
                mx[4] = fmaxf(mx[4] * r, p * bflo(cur.z));
                mx[5] = fmaxf(mx[5] * r, p * bfhi(cur.z));
                mx[6] = fmaxf(mx[6] * r, p * bflo(cur.w));
                m = mn;
            }
        }
        float rd = 1.f / den;
        #pragma unroll
        for (int c2 = 0; c2 < C; ++c2) vals[nl][h * C + c2] = mx[c2] * rd;
    }
    __syncthreads();

    if (t < NPB * C) {
        int nl2 = t / C, c2 = t - nl2 * C;
        int n2 = blockIdx.x * NPB + nl2;
        if (n2 < N) {
            float s = 0.f;
            #pragma unroll
            for (int hh = 0; hh < H; ++hh) s += vals[nl2][hh * C + c2];
            float o = s * (1.f / H) + bias[c2];
            if (LAYER == 1) h1[(size_t)n2 * C + c2] = fmaxf(o, 0.f);
            else            fv[nl2][c2] = o;
        }
    }
    if (LAYER == 2) {
        __syncthreads();
        if (t < NPB) {
            int n2 = blockIdx.x * NPB + t;
            if (n2 < N) {
                float mv = -1e30f;
                #pragma unroll
                for (int c2 = 0; c2 < C; ++c2) mv = fmaxf(mv, fv[t][c2]);
                float lse = 0.f;
                #pragma unroll
                for (int c2 = 0; c2 < C; ++c2) lse += __expf(fv[t][c2] - mv);
                lse = logf(lse);
                #pragma unroll
                for (int c2 = 0; c2 < C; ++c2)
                    out[(size_t)n2 * C + c2] = fv[t][c2] - mv - lse;
            }
        }
    }
}

// ---------------- launch ----------------

static inline size_t align16(size_t v) { return (v + 15) & ~(size_t)15; }

extern "C" void kernel_launch(void* const* d_in, const int* in_sizes, int n_in,
                              void* d_out, int out_size, void* d_ws, size_t ws_size,
                              hipStream_t stream)
{
    const float* x     = (const float*)d_in[0];
    const int*   ei    = (const int*)d_in[1];
    const float* W1    = (const float*)d_in[2];
    const float* asrc1 = (const float*)d_in[3];
    const float* adst1 = (const float*)d_in[4];
    const float* b1    = (const float*)d_in[5];
    const float* W2    = (const float*)d_in[6];
    const float* asrc2 = (const float*)d_in[7];
    const float* adst2 = (const float*)d_in[8];
    const float* b2    = (const float*)d_in[9];

    const int N  = in_sizes[0] / FIN;   // 100000
    const int E  = in_sizes[1] / 2;     // 1600000
    const int nb = (N + BSIZE - 1) >> BSHIFT;   // 196

    char* w = (char*)d_ws;
    uint4* xpack   = (uint4*)w; w += align16((size_t)N * H * 16);   // 22.4 MB
    int2*  pedge   = (int2*)w;  w += align16((size_t)E * 8);        // 12.8 MB
    float* aldst   = (float*)w; w += align16((size_t)N * H * 4);    //  5.6 MB
    float* h1      = (float*)w; w += align16((size_t)N * C * 4);    //  2.8 MB
    int*   row_ptr = (int*)w;   w += align16((size_t)(N + 1) * 4);
    int*   col     = (int*)w;   w += align16((size_t)E * 4);        //  6.4 MB
    int*   gcnt    = (int*)w;   w += align16((size_t)nb * 4);
    int*   boff    = (int*)w;   w += align16((size_t)(nb + 1) * 4);
    int*   bcur    = (int*)w;   w += align16((size_t)nb * 4);
    unsigned short* WtG = (unsigned short*)w; w += align16((size_t)WT_ROWS * FIN * 2);

    const int gAgg  = (N + NPB - 1) / NPB;
    const int gMfma = (N + 63) / 64;
    const int g256N = (N + 255) / 256;

    // ---- bucketed CSR build (no self loops; rebuilt every call) ----
    k_zero<<<1, 256, 0, stream>>>(gcnt, nb);
    k_hist<<<256, 256, 0, stream>>>(ei, E, gcnt, nb);
    k_bscan<<<1, 1024, 0, stream>>>(gcnt, boff, bcur, row_ptr, nb, N);
    k_part<<<256, 256, 0, stream>>>(ei, E, bcur, pedge, nb);
    k_bcsr<<<nb, 512, 0, stream>>>(pedge, boff, row_ptr, col, N);

    // ---- layer 1 ----
    k_convW<<<(WT_ROWS * FIN + 255) / 256, 256, 0, stream>>>(W1, WtG);
    k_proj1_mfma<<<gMfma, 256, 0, stream>>>(x, WtG, asrc1, adst1, xpack, aldst, N);
    k_agg<1><<<gAgg, AGG_BLOCK, 0, stream>>>(row_ptr, col, xpack, aldst, b1,
                                             h1, (float*)d_out, N);
    // ---- layer 2 ----
    k_proj2_pack<<<g256N, 256, 0, stream>>>(h1, W2, asrc2, adst2, xpack, aldst, N);
    k_agg<2><<<gAgg, AGG_BLOCK, 0, stream>>>(row_ptr, col, xpack, aldst, b2,
                                             h1, (float*)d_out, N);
}

// Round 10
// 411.159 us; speedup vs baseline: 1.7381x; 1.1656x over previous
//
#include <hip/hip_runtime.h>
#include <math.h>

#define H  14
#define C  7
#define HC 98
#define FIN 256
#define NEG_SLOPE 0.2f
#define NPB 32
#define AGG_BLOCK (NPB * H)   // 448 = 7 full waves

#define BSHIFT 9
#define BSIZE  512
#define NBUCK_MAX 256

typedef __attribute__((ext_vector_type(8))) short short8;
typedef __attribute__((ext_vector_type(4))) float floatx4;

#define WT_ROWS   112            // 98 cols zero-padded to 7*16
#define WT_STRIDE 264            // 256 + 8 pad (bf16 units)
#define XA_STRIDE 40             // 32 + 8 pad (bf16 units)
#define VS_STRIDE 99             // 98 + 1 pad (f32 units)

// f32 -> bf16 bits, round-to-nearest-even
__device__ __forceinline__ unsigned bf16r(float f) {
    unsigned u = __float_as_uint(f);
    return (u + 0x7FFFu + ((u >> 16) & 1u)) >> 16;
}
__device__ __forceinline__ float bflo(unsigned w) { return __uint_as_float(w << 16); }
__device__ __forceinline__ float bfhi(unsigned w) { return __uint_as_float(w & 0xFFFF0000u); }

// ---------------- bucketed CSR construction (no self loops) ----------------

__global__ void k_zero(int* __restrict__ p, int n) {
    int i = blockIdx.x * blockDim.x + threadIdx.x;
    if (i < n) p[i] = 0;
}

__global__ __launch_bounds__(256) void k_hist(const int* __restrict__ ei, int E,
                                              int* __restrict__ gcnt, int nb) {
    __shared__ int hist[NBUCK_MAX];
    const int t = threadIdx.x;
    for (int i = t; i < nb; i += 256) hist[i] = 0;
    __syncthreads();
    const int stride = gridDim.x * 256;
    for (int e = blockIdx.x * 256 + t; e < E; e += stride)
        atomicAdd(&hist[ei[E + e] >> BSHIFT], 1);
    __syncthreads();
    for (int i = t; i < nb; i += 256)
        if (hist[i]) atomicAdd(gcnt + i, hist[i]);
}

__global__ __launch_bounds__(1024) void k_bscan(const int* __restrict__ gcnt,
                                                int* __restrict__ boff, int* __restrict__ bcur,
                                                int* __restrict__ row_ptr, int nb, int N) {
    __shared__ int sd[1024];
    int t = threadIdx.x;
    int own = (t < nb) ? gcnt[t] : 0;
    sd[t] = own;
    __syncthreads();
    #pragma unroll
    for (int off = 1; off < 1024; off <<= 1) {
        int v = (t >= off) ? sd[t - off] : 0;
        __syncthreads();
        sd[t] += v;
        __syncthreads();
    }
    if (t < nb) {
        boff[t + 1] = sd[t];
        bcur[t] = sd[t] - own;          // exclusive
        if (t == nb - 1) row_ptr[N] = sd[t];
    }
    if (t == 0) boff[0] = 0;
}

__global__ __launch_bounds__(256) void k_part(const int* __restrict__ ei, int E,
                                              int* __restrict__ bcur, int2* __restrict__ pedge,
                                              int nb) {
    __shared__ int hist[NBUCK_MAX];
    __shared__ int start[NBUCK_MAX];
    const int t = threadIdx.x;
    const int chunk = (E + gridDim.x - 1) / gridDim.x;
    const int c0 = blockIdx.x * chunk;
    const int c1 = min(c0 + chunk, E);
    for (int i = t; i < nb; i += 256) hist[i] = 0;
    __syncthreads();
    for (int e = c0 + t; e < c1; e += 256)
        atomicAdd(&hist[ei[E + e] >> BSHIFT], 1);
    __syncthreads();
    for (int i = t; i < nb; i += 256) {
        int h = hist[i];
        start[i] = h ? atomicAdd(bcur + i, h) : 0;
        hist[i] = 0;                     // reuse as local cursor
    }
    __syncthreads();
    for (int e = c0 + t; e < c1; e += 256) {
        int s = ei[e], d = ei[E + e];
        int b = d >> BSHIFT;
        int pos = start[b] + atomicAdd(&hist[b], 1);
        pedge[pos] = make_int2(s, d);
    }
}

__global__ __launch_bounds__(512) void k_bcsr(const int2* __restrict__ pedge,
                                              const int* __restrict__ boff,
                                              int* __restrict__ row_ptr, int* __restrict__ col,
                                              int N) {
    __shared__ int cnt[BSIZE];
    __shared__ int sc[BSIZE];
    __shared__ int cur[BSIZE];
    const int b  = blockIdx.x;
    const int t  = threadIdx.x;
    const int e0 = boff[b], e1 = boff[b + 1];
    const int base = b << BSHIFT;
    const int nv = min(BSIZE, N - base);
    cnt[t] = 0;
    __syncthreads();
    for (int e = e0 + t; e < e1; e += 512)
        atomicAdd(&cnt[pedge[e].y - base], 1);
    __syncthreads();
    sc[t] = cnt[t];
    __syncthreads();
    #pragma unroll
    for (int off = 1; off < BSIZE; off <<= 1) {
        int v = (t >= off) ? sc[t - off] : 0;
        __syncthreads();
        sc[t] += v;
        __syncthreads();
    }
    if (t < nv) {
        int excl = sc[t] - cnt[t];
        row_ptr[base + t] = e0 + excl;
        cur[t] = excl;
    }
    __syncthreads();
    for (int e = e0 + t; e < e1; e += 512) {
        int2 r = pedge[e];
        int d = r.y - base;
        int pos = e0 + atomicAdd(&cur[d], 1);
        col[pos] = r.x;
    }
}

// ---------------- layer-1: MFMA projection fused with pack ----------------

__global__ void k_convW(const float* __restrict__ W, unsigned short* __restrict__ WtG) {
    int id = blockIdx.x * blockDim.x + threadIdx.x;   // 112*256
    int n = id >> 8, k = id & 255;
    float v = (n < HC) ? W[k * HC + n] : 0.f;
    WtG[id] = (unsigned short)(__float_as_uint(v) >> 16);  // exact: inputs bf16-rounded
}

// xpack[n*H+h] = {7 msg bf16, src-logit bf16}; aldst[n*H+h] = dst logit f32
__global__ __launch_bounds__(256) void k_proj1_mfma(
    const float* __restrict__ x, const unsigned short* __restrict__ WtG,
    const float* __restrict__ asrc, const float* __restrict__ adst,
    uint4* __restrict__ xpack, float* __restrict__ aldst, int N)
{
    __shared__ unsigned short wt_s[WT_ROWS * WT_STRIDE];  // 59136 B (reused as f32 vals)
    __shared__ unsigned short xa_s[64 * XA_STRIDE];       //  5120 B
    __shared__ float as_s[HC], ad_s[HC];
    float* vals_s = (float*)wt_s;                          // 64*99*4 = 25344 B < 59136
    const int t  = threadIdx.x;
    const int wv = t >> 6;
    const int l  = t & 63;
    const int ln = l & 15;
    const int qd = l >> 4;
    const int rowBase = blockIdx.x * 64;

    #pragma unroll
    for (int i = 0; i < 14; ++i) {
        int f = i * 256 + t;            // uint4 index, 3584 total (32 per row)
        int r = f >> 5, pos = f & 31;
        *(uint4*)(wt_s + r * WT_STRIDE + pos * 8) = ((const uint4*)WtG)[f];
    }
    if (t < HC) { as_s[t] = asrc[t]; ad_s[t] = adst[t]; }

    floatx4 acc[7] = {};

    for (int step = 0; step < 8; ++step) {
        const int k0 = step * 32;
        __syncthreads();
        #pragma unroll
        for (int i = 0; i < 2; ++i) {
            int idx = i * 256 + t;       // 512 float4 total
            int r = idx >> 3, c4 = idx & 7;
            int gr = rowBase + r; if (gr >= N) gr = N - 1;
            float4 v = *(const float4*)(x + (size_t)gr * FIN + k0 + c4 * 4);
            ushort4 u;
            u.x = (unsigned short)(__float_as_uint(v.x) >> 16);
            u.y = (unsigned short)(__float_as_uint(v.y) >> 16);
            u.z = (unsigned short)(__float_as_uint(v.z) >> 16);
            u.w = (unsigned short)(__float_as_uint(v.w) >> 16);
            *(ushort4*)(xa_s + r * XA_STRIDE + c4 * 4) = u;
        }
        __syncthreads();
        short8 a = *(const short8*)(xa_s + ((wv << 4) + ln) * XA_STRIDE + qd * 8);
        #pragma unroll
        for (int ct = 0; ct < 7; ++ct) {
            short8 b = *(const short8*)(wt_s + (ct * 16 + ln) * WT_STRIDE + k0 + qd * 8);
            acc[ct] = __builtin_amdgcn_mfma_f32_16x16x32_bf16(a, b, acc[ct], 0, 0, 0);
        }
    }

    __syncthreads();                    // wt_s dead; reuse as vals_s
    // C/D: col = ln, row = qd*4 + r (local row = wv*16 + qd*4 + r)
    #pragma unroll
    for (int ct = 0; ct < 7; ++ct) {
        int colg = ct * 16 + ln;
        if (colg < HC) {
            #pragma unroll
            for (int r = 0; r < 4; ++r)
                vals_s[((wv << 4) + (qd << 2) + r) * VS_STRIDE + colg] = acc[ct][r];
        }
    }
    __syncthreads();

    // pack: 64 nodes x 14 heads = 896 records
    for (int p = t; p < 64 * H; p += 256) {
        int nl = p / H, h = p - nl * H;
        int gn = rowBase + nl;
        if (gn >= N) break;
        const float* vp = vals_s + nl * VS_STRIDE + h * C;
        unsigned v[C];
        float s1 = 0.f, s2 = 0.f;
        #pragma unroll
        for (int c2 = 0; c2 < C; ++c2) {
            float f = vp[c2];
            v[c2] = bf16r(f);
            s1 = fmaf(f, as_s[h * C + c2], s1);
            s2 = fmaf(f, ad_s[h * C + c2], s2);
        }
        uint4 pk;
        pk.x = v[0] | (v[1] << 16);
        pk.y = v[2] | (v[3] << 16);
        pk.z = v[4] | (v[5] << 16);
        pk.w = v[6] | (bf16r(s1) << 16);
        xpack[(size_t)gn * H + h] = pk;
        aldst[(size_t)gn * H + h] = s2;
    }
}

// ---------------- layer-2 projection + pack (thread per node) ----------------

__global__ __launch_bounds__(256) void k_proj2_pack(
    const float* __restrict__ h1, const float* __restrict__ W,
    const float* __restrict__ asrc, const float* __restrict__ adst,
    uint4* __restrict__ xpack, float* __restrict__ aldst, int N)
{
    __shared__ float Ws[C * HC];
    __shared__ float as_s[HC], ad_s[HC];
    const int t = threadIdx.x;
    for (int i = t; i < C * HC; i += 256) Ws[i] = W[i];
    if (t < HC) { as_s[t] = asrc[t]; ad_s[t] = adst[t]; }
    __syncthreads();
    int n = blockIdx.x * 256 + t;
    if (n >= N) return;
    float xr[C];
    #pragma unroll
    for (int c2 = 0; c2 < C; ++c2) xr[c2] = h1[(size_t)n * C + c2];
    #pragma unroll
    for (int h = 0; h < H; ++h) {
        float v[C], s1 = 0.f, s2 = 0.f;
        #pragma unroll
        for (int c2 = 0; c2 < C; ++c2) {
            float acc = 0.f;
            #pragma unroll
            for (int k = 0; k < C; ++k)
                acc = fmaf(xr[k], Ws[k * HC + h * C + c2], acc);
            v[c2] = acc;
            s1 = fmaf(acc, as_s[h * C + c2], s1);
            s2 = fmaf(acc, ad_s[h * C + c2], s2);
        }
        uint4 pk;
        pk.x = bf16r(v[0]) | (bf16r(v[1]) << 16);
        pk.y = bf16r(v[2]) | (bf16r(v[3]) << 16);
        pk.z = bf16r(v[4]) | (bf16r(v[5]) << 16);
        pk.w = bf16r(v[6]) | (bf16r(s1) << 16);
        xpack[(size_t)n * H + h] = pk;     // 224 B contiguous per thread
        aldst[(size_t)n * H + h] = s2;
    }
}

// ---------------- fused aggregation ----------------
// thread = (node, head); implicit self loop; TWO independent online-softmax
// streams (ILP x2) + decoupled col queue 4 ahead of the record pipeline.

#define AGG_STEP(MM, DEN, MX, REC)                                   \
    {                                                                \
        float l = bfhi((REC).w) + ld;                                \
        l = (l > 0.f) ? l : NEG_SLOPE * l;                           \
        float mn = fmaxf(MM, l);                                     \
        float r  = __expf(MM - mn);                                  \
        float p  = __expf(l - mn);                                   \
        DEN = DEN * r + p;                                           \
        MX[0] = fmaxf(MX[0] * r, p * bflo((REC).x));                 \
        MX[1] = fmaxf(MX[1] * r, p * bfhi((REC).x));                 \
        MX[2] = fmaxf(MX[2] * r, p * bflo((REC).y));                 \
        MX[3] = fmaxf(MX[3] * r, p * bfhi((REC).y));                 \
        MX[4] = fmaxf(MX[4] * r, p * bflo((REC).z));                 \
        MX[5] = fmaxf(MX[5] * r, p * bfhi((REC).z));                 \
        MX[6] = fmaxf(MX[6] * r, p * bflo((REC).w));                 \
        MM = mn;                                                     \
    }

template<int LAYER>
__global__ __launch_bounds__(AGG_BLOCK) void k_agg(
    const int* __restrict__ row_ptr, const int* __restrict__ col,
    const uint4* __restrict__ xpack, const float* __restrict__ aldst,
    const float* __restrict__ bias,
    float* __restrict__ h1, float* __restrict__ out, int N)
{
    __shared__ float vals[NPB][HC];
    __shared__ float fv[NPB][C];
    const int t  = threadIdx.x;
    const int nl = t / H;
    const int h  = t - nl * H;
    const int n  = blockIdx.x * NPB + nl;

    if (n < N) {
        const int e0  = row_ptr[n];
        const int deg = row_ptr[n + 1] - e0;
        const float ld = aldst[(size_t)n * H + h];

        // state A init: implicit self loop
        float mA, denA, mxA[C];
        {
            uint4 pk = xpack[(size_t)n * H + h];
            float l = bfhi(pk.w) + ld;
            l = (l > 0.f) ? l : NEG_SLOPE * l;
            mA = l; denA = 1.f;
            mxA[0] = bflo(pk.x); mxA[1] = bfhi(pk.x);
            mxA[2] = bflo(pk.y); mxA[3] = bfhi(pk.y);
            mxA[4] = bflo(pk.z); mxA[5] = bfhi(pk.z);
            mxA[6] = bflo(pk.w);
        }

        if (deg > 0) {
            const int last = deg - 1;
            // state B init: edge 0
            float mB, denB, mxB[C];
            {
                uint4 pk = xpack[(size_t)col[e0] * H + h];
                float l = bfhi(pk.w) + ld;
                l = (l > 0.f) ? l : NEG_SLOPE * l;
                mB = l; denB = 1.f;
                mxB[0] = bflo(pk.x); mxB[1] = bfhi(pk.x);
                mxB[2] = bflo(pk.y); mxB[3] = bfhi(pk.y);
                mxB[4] = bflo(pk.z); mxB[5] = bfhi(pk.z);
                mxB[6] = bflo(pk.w);
            }
            // record pipeline (indices 1..last), col queue 4 ahead
            int c0 = col[e0 + min(1, last)];
            int c1 = col[e0 + min(2, last)];
            int c2 = col[e0 + min(3, last)];
            int c3 = col[e0 + min(4, last)];
            uint4 r0 = xpack[(size_t)c0 * H + h];
            uint4 r1 = xpack[(size_t)c1 * H + h];
            uint4 r2 = xpack[(size_t)c2 * H + h];
            uint4 r3 = xpack[(size_t)c3 * H + h];
            c0 = col[e0 + min(5, last)];
            c1 = col[e0 + min(6, last)];
            c2 = col[e0 + min(7, last)];
            c3 = col[e0 + min(8, last)];
            for (int i = 1; i < deg; i += 2) {
                uint4 curA = r0, curB = r1;
                r0 = r2; r1 = r3;
                r2 = xpack[(size_t)c0 * H + h];
                r3 = xpack[(size_t)c1 * H + h];
                c0 = c2; c1 = c3;
                c2 = col[e0 + min(i + 8, last)];
                c3 = col[e0 + min(i + 9, last)];
                AGG_STEP(mA, denA, mxA, curA);            // index i
                if (i + 1 < deg) AGG_STEP(mB, denB, mxB, curB);  // index i+1
            }
            // merge B into A
            float mn = fmaxf(mA, mB);
            float rA = __expf(mA - mn), rB = __expf(mB - mn);
            denA = denA * rA + denB * rB;
            #pragma unroll
            for (int c4 = 0; c4 < C; ++c4)
                mxA[c4] = fmaxf(mxA[c4] * rA, mxB[c4] * rB);
        }

        float rd = 1.f / denA;
        #pragma unroll
        for (int c2 = 0; c2 < C; ++c2) vals[nl][h * C + c2] = mxA[c2] * rd;
    }
    __syncthreads();

    if (t < NPB * C) {
        int nl2 = t / C, c2 = t - nl2 * C;
        int n2 = blockIdx.x * NPB + nl2;
        if (n2 < N) {
            float s = 0.f;
            #pragma unroll
            for (int hh = 0; hh < H; ++hh) s += vals[nl2][hh * C + c2];
            float o = s * (1.f / H) + bias[c2];
            if (LAYER == 1) h1[(size_t)n2 * C + c2] = fmaxf(o, 0.f);
            else            fv[nl2][c2] = o;
        }
    }
    if (LAYER == 2) {
        __syncthreads();
        if (t < NPB) {
            int n2 = blockIdx.x * NPB + t;
            if (n2 < N) {
                float mv = -1e30f;
                #pragma unroll
                for (int c2 = 0; c2 < C; ++c2) mv = fmaxf(mv, fv[t][c2]);
                float lse = 0.f;
                #pragma unroll
                for (int c2 = 0; c2 < C; ++c2) lse += __expf(fv[t][c2] - mv);
                lse = logf(lse);
                #pragma unroll
                for (int c2 = 0; c2 < C; ++c2)
                    out[(size_t)n2 * C + c2] = fv[t][c2] - mv - lse;
            }
        }
    }
}

// ---------------- launch ----------------

static inline size_t align16(size_t v) { return (v + 15) & ~(size_t)15; }

extern "C" void kernel_launch(void* const* d_in, const int* in_sizes, int n_in,
                              void* d_out, int out_size, void* d_ws, size_t ws_size,
                              hipStream_t stream)
{
    const float* x     = (const float*)d_in[0];
    const int*   ei    = (const int*)d_in[1];
    const float* W1    = (const float*)d_in[2];
    const float* asrc1 = (const float*)d_in[3];
    const float* adst1 = (const float*)d_in[4];
    const float* b1    = (const float*)d_in[5];
    const float* W2    = (const float*)d_in[6];
    const float* asrc2 = (const float*)d_in[7];
    const float* adst2 = (const float*)d_in[8];
    const float* b2    = (const float*)d_in[9];

    const int N  = in_sizes[0] / FIN;   // 100000
    const int E  = in_sizes[1] / 2;     // 1600000
    const int nb = (N + BSIZE - 1) >> BSHIFT;   // 196

    char* w = (char*)d_ws;
    uint4* xpack   = (uint4*)w; w += align16((size_t)N * H * 16);   // 22.4 MB
    int2*  pedge   = (int2*)w;  w += align16((size_t)E * 8);        // 12.8 MB
    float* aldst   = (float*)w; w += align16((size_t)N * H * 4);    //  5.6 MB
    float* h1      = (float*)w; w += align16((size_t)N * C * 4);    //  2.8 MB
    int*   row_ptr = (int*)w;   w += align16((size_t)(N + 1) * 4);
    int*   col     = (int*)w;   w += align16((size_t)E * 4);        //  6.4 MB
    int*   gcnt    = (int*)w;   w += align16((size_t)nb * 4);
    int*   boff    = (int*)w;   w += align16((size_t)(nb + 1) * 4);
    int*   bcur    = (int*)w;   w += align16((size_t)nb * 4);
    unsigned short* WtG = (unsigned short*)w; w += align16((size_t)WT_ROWS * FIN * 2);

    const int gAgg  = (N + NPB - 1) / NPB;
    const int gMfma = (N + 63) / 64;
    const int g256N = (N + 255) / 256;

    // ---- bucketed CSR build (no self loops; rebuilt every call) ----
    k_zero<<<1, 256, 0, stream>>>(gcnt, nb);
    k_hist<<<256, 256, 0, stream>>>(ei, E, gcnt, nb);
    k_bscan<<<1, 1024, 0, stream>>>(gcnt, boff, bcur, row_ptr, nb, N);
    k_part<<<256, 256, 0, stream>>>(ei, E, bcur, pedge, nb);
    k_bcsr<<<nb, 512, 0, stream>>>(pedge, boff, row_ptr, col, N);

    // ---- layer 1 ----
    k_convW<<<(WT_ROWS * FIN + 255) / 256, 256, 0, stream>>>(W1, WtG);
    k_proj1_mfma<<<gMfma, 256, 0, stream>>>(x, WtG, asrc1, adst1, xpack, aldst, N);
    k_agg<1><<<gAgg, AGG_BLOCK, 0, stream>>>(row_ptr, col, xpack, aldst, b1,
                                             h1, (float*)d_out, N);
    // ---- layer 2 ----
    k_proj2_pack<<<g256N, 256, 0, stream>>>(h1, W2, asrc2, adst2, xpack, aldst, N);
    k_agg<2><<<gAgg, AGG_BLOCK, 0, stream>>>(row_ptr, col, xpack, aldst, b2,
                                             h1, (float*)d_out, N);
}